// Round 6
// baseline (286.321 us; speedup 1.0000x reference)
//
#include <hip/hip_runtime.h>
#include <cstdint>

typedef unsigned short u16;
typedef uint32_t u32;
typedef __attribute__((ext_vector_type(8))) short bf16x8;
typedef __attribute__((ext_vector_type(4))) float f32x4;
typedef __attribute__((ext_vector_type(16))) float f32x16;

#define DIM_ 2048
#define S_   2048
#define B_   2
#define H_   16
#define HD_  128
#define M_   (B_ * S_)  // 4096

// ---------- scalar bf16 helpers (RNE) ----------
__device__ __forceinline__ u16 f2b(float f) {
  union { float f; uint32_t u; } v; v.f = f;
  uint32_t u = v.u;
  return (u16)((u + 0x7FFFu + ((u >> 16) & 1u)) >> 16);
}
__device__ __forceinline__ float b2f(u16 h) {
  union { uint32_t u; float f; } v; v.u = ((uint32_t)h) << 16;
  return v.f;
}

// pack 2 f32 -> 2 bf16 in one u32 (lo = first arg)
__device__ __forceinline__ u32 cvtpk(float lo, float hi) {
  u32 r;
  asm("v_cvt_pk_bf16_f32 %0, %1, %2" : "=v"(r) : "v"(lo), "v"(hi));
  return r;
}

// ---------- global -> LDS async copy (16B per lane, wave-uniform LDS base) ----------
typedef __attribute__((address_space(3))) u16 lds_u16_t;
typedef __attribute__((address_space(1))) const u16 glob_u16_t;

__device__ __forceinline__ void gload16(const u16* g, u16* l) {
  __builtin_amdgcn_global_load_lds((glob_u16_t*)g, (lds_u16_t*)l, 16, 0, 0);
}
// offset folded via pointer arithmetic; builtin offset stays 0 (the validated path)
#define GLD0(SRC, DST) \
  __builtin_amdgcn_global_load_lds((glob_u16_t*)(SRC), (lds_u16_t*)(DST), 16, 0, 0)

// ---------- fp32 -> bf16 convert, 5 buffers in one launch ----------
__global__ void convert5_kernel(const float* __restrict__ x, const float* __restrict__ wq,
                                const float* __restrict__ wk, const float* __restrict__ wv,
                                const float* __restrict__ wo, u16* __restrict__ xb,
                                u16* __restrict__ wqb, u16* __restrict__ wkb,
                                u16* __restrict__ wvb, u16* __restrict__ wob) {
  const float* src;
  u16* dst;
  int n;
  switch (blockIdx.y) {
    case 0: src = x;  dst = xb;  n = M_ * DIM_;   break;
    case 1: src = wq; dst = wqb; n = DIM_ * DIM_; break;
    case 2: src = wk; dst = wkb; n = DIM_ * DIM_; break;
    case 3: src = wv; dst = wvb; n = DIM_ * DIM_; break;
    default: src = wo; dst = wob; n = DIM_ * DIM_; break;
  }
  int i = (blockIdx.x * blockDim.x + threadIdx.x) * 4;
  const int stride = gridDim.x * blockDim.x * 4;
  for (; i < n; i += stride) {
    float4 v = *reinterpret_cast<const float4*>(src + i);
    uint64_t p = (uint64_t)f2b(v.x) | ((uint64_t)f2b(v.y) << 16) |
                 ((uint64_t)f2b(v.z) << 32) | ((uint64_t)f2b(v.w) << 48);
    *reinterpret_cast<uint64_t*>(dst + i) = p;
  }
}

// ---------- RoPE tables: cos/sin [S][64] fp32 ----------
__global__ void rope_table_kernel(float* __restrict__ cosT, float* __restrict__ sinT) {
  int i = blockIdx.x * blockDim.x + threadIdx.x;
  if (i >= S_ * 64) return;
  int s = i >> 6, d = i & 63;
  float inv = powf(10000.0f, -(float)d * (1.0f / 64.0f));
  float ang = (float)s * inv;
  cosT[i] = cosf(ang);
  sinT[i] = sinf(ang);
}

// ---------- RoPE apply (in-place, rotate-half, D=128), q and k in one launch ----------
__global__ void rope_apply_kernel(u16* __restrict__ qb, u16* __restrict__ kb,
                                  const float* __restrict__ cosT,
                                  const float* __restrict__ sinT) {
  u16* buf = blockIdx.y ? kb : qb;
  int i = blockIdx.x * blockDim.x + threadIdx.x;  // over B*S*H*64
  if (i >= B_ * S_ * H_ * 64) return;
  int d = i & 63;
  int h = (i >> 6) & (H_ - 1);
  int row = i >> 10;        // b*S + s
  int s = row & (S_ - 1);
  u16* p = buf + (size_t)row * DIM_ + h * HD_ + d;
  float t1 = b2f(p[0]);
  float t2 = b2f(p[64]);
  float c = cosT[s * 64 + d];
  float sn = sinT[s * 64 + d];
  p[0]  = f2b(t1 * c - t2 * sn);
  p[64] = f2b(t2 * c + t1 * sn);
}

// ==================================================================================
// QKV GEMM: 256x256 tile, BK=64, 512 thr = 8 waves (2M x 4N), wave tile 128x64.
// 4 phases/K-tile, quadrants (0,0)->(0,1)->(1,1)->(1,0) (B-q0 re-read at P3).
// STAGING IS BY QUADRANT ROW-UNION (not contiguous halves!):
//   A-quad q rows = {q*64..q*64+63} u {128+q*64..128+q*64+63}   (2 sweeps)
//   B-quad q rows = {s*128 + j*64 + q*32 + r32}                  (4 stripes of 32)
// so every stage target's LAST LDS reader is a FULL PHASE (barrier+lgkmcnt) earlier:
//   P0: reads Aq0,Bq0; stage Bq0(t+1)->buf^1   [Bq0 last read P3(t-1), barrier sep]
//   P1: reads Bq1;     stage Aq0(t+2)->cur     [Aq0 last read P0]
//   P2: reads Aq1;     stage Bq1(t+2)->cur     [Bq1 last read P1]
//   P3: reads Bq0;     stage Aq1(t+2)->cur     [Aq1 last read P2]
// vmcnt(6) once per K-tile at P3 (drains tile t+1 exactly); vmcnt(0) at NT-2.
// LDS 128KB: buf*32768 + [A 256x64 | B 256x64] u16, row-major, chunk-XOR swizzle
// (slot = chunk ^ row&7). All k-offsets via pointer arithmetic (builtin offset = 0).
// ==================================================================================
#define NT_ 32  // 2048 / 64

#define STAGE_A(BUF, Q, OFFU) do {                                             \
    GLD0(sAq##Q##0 + (OFFU), lds + (BUF)*32768 + (Q)*4096 + waA);              \
    GLD0(sAq##Q##1 + (OFFU), lds + (BUF)*32768 + (Q)*4096 + 8192 + waA);       \
  } while (0)
#define STAGE_B(BUF, Q, OFFU) do {                                             \
    GLD0(sBq##Q##0 + (OFFU), lds + (BUF)*32768 + 16384 + (Q)*2048 + waB);      \
    GLD0(sBq##Q##1 + (OFFU), lds + (BUF)*32768 + 16384 + 8192 + (Q)*2048 + waB); \
  } while (0)

#define RD_A(BUF, KS, MH, MI) (*(const bf16x8*)(pA##BUF##k##KS + (MH)*4096 + (MI)*1024))
#define RD_B(BUF, KS, NH, NI) (*(const bf16x8*)(pB##BUF##k##KS + (NH)*2048 + (NI)*1024))

#define LOAD_A(BUF, MH) do {                                                   \
    a[0] = RD_A(BUF, 0, MH, 0); a[1] = RD_A(BUF, 1, MH, 0);                    \
    a[2] = RD_A(BUF, 0, MH, 1); a[3] = RD_A(BUF, 1, MH, 1);                    \
    a[4] = RD_A(BUF, 0, MH, 2); a[5] = RD_A(BUF, 1, MH, 2);                    \
    a[6] = RD_A(BUF, 0, MH, 3); a[7] = RD_A(BUF, 1, MH, 3);                    \
  } while (0)
#define LOAD_B(BUF, NH) do {                                                   \
    b[0] = RD_B(BUF, 0, NH, 0); b[1] = RD_B(BUF, 1, NH, 0);                    \
    b[2] = RD_B(BUF, 0, NH, 1); b[3] = RD_B(BUF, 1, NH, 1);                    \
  } while (0)

#define MFMA_Q(MB, NB)                                                         \
  _Pragma("unroll")                                                            \
  for (int mi = 0; mi < 4; ++mi)                                               \
    _Pragma("unroll")                                                          \
    for (int ni = 0; ni < 2; ++ni)                                             \
      _Pragma("unroll")                                                        \
      for (int ks = 0; ks < 2; ++ks)                                           \
        acc[(MB) + mi][(NB) + ni] = __builtin_amdgcn_mfma_f32_16x16x32_bf16(   \
            a[mi * 2 + ks], b[ni * 2 + ks], acc[(MB) + mi][(NB) + ni], 0, 0, 0);

#define PH(MB, NB)                                                             \
  __builtin_amdgcn_s_barrier();                                                \
  asm volatile("s_waitcnt lgkmcnt(0)" ::: "memory");                           \
  __builtin_amdgcn_sched_barrier(0);                                           \
  __builtin_amdgcn_s_setprio(1);                                               \
  MFMA_Q(MB, NB);                                                              \
  __builtin_amdgcn_s_setprio(0);                                               \
  __builtin_amdgcn_s_barrier();

#define TILE(T, BUF, NBUF, OFF1, OFF2) do {                                    \
    /* P0: quad(0,0) */                                                        \
    LOAD_A(BUF, 0);                                                            \
    LOAD_B(BUF, 0);                                                            \
    if ((T) + 1 < NT_) STAGE_B(NBUF, 0, OFF1);                                 \
    PH(0, 0)                                                                   \
    /* P1: quad(0,1), A-q0 held in regs */                                     \
    LOAD_B(BUF, 1);                                                            \
    if ((T) + 2 < NT_) STAGE_A(BUF, 0, OFF2);                                  \
    PH(0, 2)                                                                   \
    /* P2: quad(1,1), B-q1 held */                                             \
    LOAD_A(BUF, 1);                                                            \
    if ((T) + 2 < NT_) STAGE_B(BUF, 1, OFF2);                                  \
    PH(4, 2)                                                                   \
    /* P3: quad(1,0), A-q1 held, B-q0 re-read; counted vmcnt once per K-tile */ \
    LOAD_B(BUF, 0);                                                            \
    if ((T) + 2 < NT_) STAGE_A(BUF, 1, OFF2);                                  \
    __builtin_amdgcn_s_barrier();                                              \
    asm volatile("s_waitcnt lgkmcnt(0)" ::: "memory");                         \
    __builtin_amdgcn_sched_barrier(0);                                         \
    __builtin_amdgcn_s_setprio(1);                                             \
    MFMA_Q(4, 0);                                                              \
    __builtin_amdgcn_s_setprio(0);                                             \
    __builtin_amdgcn_sched_barrier(0);                                         \
    if ((T) < NT_ - 2) {                                                       \
      asm volatile("s_waitcnt vmcnt(6)" ::: "memory");                         \
    } else if ((T) == NT_ - 2) {                                               \
      asm volatile("s_waitcnt vmcnt(0)" ::: "memory");                         \
    }                                                                          \
    __builtin_amdgcn_sched_barrier(0);                                         \
    __builtin_amdgcn_s_barrier();                                              \
  } while (0)

__global__ __launch_bounds__(512, 2) void gemm256_qkv_kernel(
    const u16* __restrict__ xb, const u16* __restrict__ wqb, const u16* __restrict__ wkb,
    const u16* __restrict__ wvb, u16* __restrict__ qb, u16* __restrict__ kb,
    u16* __restrict__ vb) {
  __shared__ __align__(16) u16 lds[65536];  // 128 KB

  // XCD swizzle (384 % 8 == 0) + A-panel grouping: logical = mt*24 + z*8 + nt
  const int bid = blockIdx.x;
  const int logical = (bid & 7) * 48 + (bid >> 3);
  const int mt = logical / 24;
  const int rem = logical % 24;
  const int z = rem >> 3;
  const int nt = rem & 7;
  const u16* W = (z == 0) ? wqb : (z == 1) ? wkb : wvb;
  u16* out = (z == 0) ? qb : (z == 1) ? kb : vb;

  const int tid = threadIdx.x;
  const int lane = tid & 63;
  const int w = tid >> 6;
  const int wm = w >> 2, wn = w & 3;
  const int l15 = lane & 15, lg = lane >> 4;

  const u16* Ag = xb + (size_t)(mt * 256) * DIM_;
  const u16* Bg = W + (size_t)(nt * 256) * DIM_;

  // ---- wave-uniform LDS stage bases (u16) ----
  const int waA = w * 512;                       // A: 8 rows/wave, linear
  const int waB = (w >> 2) * 4096 + (w & 3) * 512;  // B: stripe (w>>2), sub-rows (w&3)*8

  // ---- per-lane global source pointers (inverse-swizzled chunk; rule 21) ----
  const int csw = ((lane & 7) ^ (lane >> 3)) * 8;
  // A quad-union rows: q0 sweeps -> {0..63},{128..191}; q1 -> {64..127},{192..255}
  const int arb = w * 8 + (lane >> 3);
  const u16* sAq00 = Ag + (size_t)(arb +   0) * DIM_ + csw;
  const u16* sAq01 = Ag + (size_t)(arb + 128) * DIM_ + csw;
  const u16* sAq10 = Ag + (size_t)(arb +  64) * DIM_ + csw;
  const u16* sAq11 = Ag + (size_t)(arb + 192) * DIM_ + csw;
  // B quad-stripe rows: row = s*128 + (w>>2)*64 + q*32 + (w&3)*8 + lane>>3
  const int brb = (w >> 2) * 64 + (w & 3) * 8 + (lane >> 3);
  const u16* sBq00 = Bg + (size_t)(brb +   0) * DIM_ + csw;
  const u16* sBq01 = Bg + (size_t)(brb + 128) * DIM_ + csw;
  const u16* sBq10 = Bg + (size_t)(brb +  32) * DIM_ + csw;
  const u16* sBq11 = Bg + (size_t)(brb + 160) * DIM_ + csw;

  // ---- precomputed LDS read bases (per buf, per k-slot); reads = base + imm ----
  const int x7 = l15 & 7;
  const int lr0 = l15 * 64 + ((lg ^ x7) * 8);
  const int lr1 = l15 * 64 + (((4 | lg) ^ x7) * 8);
  const u16* pA0k0 = lds + wm * 8192 + lr0;
  const u16* pA0k1 = lds + wm * 8192 + lr1;
  const u16* pA1k0 = pA0k0 + 32768;
  const u16* pA1k1 = pA0k1 + 32768;
  const u16* pB0k0 = lds + 16384 + wn * 4096 + lr0;
  const u16* pB0k1 = lds + 16384 + wn * 4096 + lr1;
  const u16* pB1k0 = pB0k0 + 32768;
  const u16* pB1k1 = pB0k1 + 32768;

  f32x4 acc[8][4];
#pragma unroll
  for (int i = 0; i < 8; ++i)
#pragma unroll
    for (int j = 0; j < 4; ++j) acc[i][j] = (f32x4){0.f, 0.f, 0.f, 0.f};

  bf16x8 a[8], b[4];

  // ---- prologue: tile0 complete (8 loads) + tile1 {Aq0, Bq1, Aq1} (6 loads);
  //      Bq0(1) staged at TILE(0) P0. FIFO order matters for vmcnt(6). ----
  STAGE_A(0, 0, 0);
  STAGE_B(0, 0, 0);
  STAGE_A(0, 1, 0);
  STAGE_B(0, 1, 0);
  STAGE_A(1, 0, 64);
  STAGE_B(1, 1, 64);
  STAGE_A(1, 1, 64);
  __builtin_amdgcn_sched_barrier(0);
  asm volatile("s_waitcnt vmcnt(6)" ::: "memory");  // tile0's 8 loads landed
  __builtin_amdgcn_sched_barrier(0);
  __builtin_amdgcn_s_barrier();

  for (int t = 0; t < NT_; t += 2) {
    TILE(t, 0, 1, 64, 128);
    TILE(t + 1, 1, 0, 128, 192);
    sAq00 += 128; sAq01 += 128; sAq10 += 128; sAq11 += 128;
    sBq00 += 128; sBq01 += 128; sBq10 += 128; sBq11 += 128;
  }

  // ---- epilogue: D layout row=(lane>>4)*4+r, col=lane&15 per 16x16 frag ----
#pragma unroll
  for (int mi = 0; mi < 8; ++mi)
#pragma unroll
    for (int ni = 0; ni < 4; ++ni) {
      const int row = mt * 256 + wm * 128 + mi * 16 + lg * 4;
      const int col = nt * 256 + wn * 64 + ni * 16 + l15;
#pragma unroll
      for (int r = 0; r < 4; ++r)
        out[(size_t)(row + r) * DIM_ + col] = f2b(acc[mi][ni][r]);
    }
}

// ==================================================================================
// O-projection: 256x128 tile 8-phase kernel (R4 structure, 256 blocks = 1 round)
// ==================================================================================
__global__ __launch_bounds__(512, 2) void gemm8_out_kernel(const u16* __restrict__ A,
                                                           const u16* __restrict__ W,
                                                           float* __restrict__ Cf) {
  __shared__ __align__(16) u16 lds[49152];  // [buf2][A 16384 | B 8192] u16 = 96 KB
  const int bid = blockIdx.x;  // 256 blocks = 1 exact round
  const int logical = (bid & 7) * 32 + (bid >> 3);
  const int mt = logical >> 4;
  const int nt = logical & 15;

  const int tid = threadIdx.x;
  const int lane = tid & 63;
  const int w = tid >> 6;
  const int wm = w >> 2, wn = w & 3;
  const int l15 = lane & 15, lg = lane >> 4;

  const u16* Ab = A + (size_t)(mt * 256) * DIM_;
  const u16* Bb = W + (size_t)(nt * 128) * DIM_;

  f32x4 acc[8][2];
#pragma unroll
  for (int i = 0; i < 8; ++i)
#pragma unroll
    for (int j = 0; j < 2; ++j) acc[i][j] = (f32x4){0.f, 0.f, 0.f, 0.f};

  auto stageA = [&](int buf, int half, int kt) {
#pragma unroll
    for (int s = 0; s < 2; ++s) {
      const int cb = s * 512 + w * 64;
      const int i = cb + lane;
      const int r = half * 128 + (i >> 3);
      const int c = (i & 7) ^ (r & 7);
      gload16(Ab + (size_t)r * DIM_ + kt * 64 + c * 8,
              lds + buf * 24576 + half * 8192 + cb * 8);
    }
  };
  auto stageB = [&](int buf, int kt) {
#pragma unroll
    for (int s = 0; s < 2; ++s) {
      const int cb = s * 512 + w * 64;
      const int i = cb + lane;
      const int r = i >> 3;
      const int c = (i & 7) ^ (r & 7);
      gload16(Bb + (size_t)r * DIM_ + kt * 64 + c * 8,
              lds + buf * 24576 + 16384 + cb * 8);
    }
  };
  auto rdA = [&](int buf, int mh, int mi, int ks) -> bf16x8 {
    const int row = wm * 128 + mh * 64 + mi * 16 + l15;
    const int chunk = ((ks << 2) + lg) ^ (l15 & 7);
    return *(const bf16x8*)(lds + buf * 24576 + row * 64 + chunk * 8);
  };
  auto rdB = [&](int buf, int ni, int ks) -> bf16x8 {
    const int row = wn * 32 + ni * 16 + l15;
    const int chunk = ((ks << 2) + lg) ^ (l15 & 7);
    return *(const bf16x8*)(lds + buf * 24576 + 16384 + row * 64 + chunk * 8);
  };

  bf16x8 a[8], b[4];

  auto phase0 = [&](int t, int cur, bool stg, int wv) {
#pragma unroll
    for (int ni = 0; ni < 2; ++ni)
#pragma unroll
      for (int ks = 0; ks < 2; ++ks) b[ni * 2 + ks] = rdB(cur, ni, ks);
#pragma unroll
    for (int mi = 0; mi < 4; ++mi)
#pragma unroll
      for (int ks = 0; ks < 2; ++ks) a[mi * 2 + ks] = rdA(cur, 0, mi, ks);
    if (stg) stageA(cur ^ 1, 1, t + 1);
    __builtin_amdgcn_s_barrier();
    asm volatile("s_waitcnt lgkmcnt(0)" ::: "memory");
    __builtin_amdgcn_sched_barrier(0);
    __builtin_amdgcn_s_setprio(1);
#pragma unroll
    for (int mi = 0; mi < 4; ++mi)
#pragma unroll
      for (int ni = 0; ni < 2; ++ni)
#pragma unroll
        for (int ks = 0; ks < 2; ++ks)
          acc[mi][ni] = __builtin_amdgcn_mfma_f32_16x16x32_bf16(a[mi * 2 + ks],
                                                                b[ni * 2 + ks],
                                                                acc[mi][ni], 0, 0, 0);
    __builtin_amdgcn_s_setprio(0);
    __builtin_amdgcn_sched_barrier(0);
    if (wv == 6) asm volatile("s_waitcnt vmcnt(6)" ::: "memory");
    else         asm volatile("s_waitcnt vmcnt(0)" ::: "memory");
    __builtin_amdgcn_sched_barrier(0);
    __builtin_amdgcn_s_barrier();
  };
  auto phase1 = [&](int t, int cur, bool stg, int wv) {
#pragma unroll
    for (int mi = 0; mi < 4; ++mi)
#pragma unroll
      for (int ks = 0; ks < 2; ++ks) a[mi * 2 + ks] = rdA(cur, 1, mi, ks);
    if (stg) { stageB(cur, t + 2); stageA(cur, 0, t + 2); }
    __builtin_amdgcn_s_barrier();
    asm volatile("s_waitcnt lgkmcnt(0)" ::: "memory");
    __builtin_amdgcn_sched_barrier(0);
    __builtin_amdgcn_s_setprio(1);
#pragma unroll
    for (int mi = 0; mi < 4; ++mi)
#pragma unroll
      for (int ni = 0; ni < 2; ++ni)
#pragma unroll
        for (int ks = 0; ks < 2; ++ks)
          acc[4 + mi][ni] = __builtin_amdgcn_mfma_f32_16x16x32_bf16(a[mi * 2 + ks],
                                                                    b[ni * 2 + ks],
                                                                    acc[4 + mi][ni], 0, 0, 0);
    __builtin_amdgcn_s_setprio(0);
    if (wv >= 0) {
      __builtin_amdgcn_sched_barrier(0);
      if (wv == 6)      asm volatile("s_waitcnt vmcnt(6)" ::: "memory");
      else if (wv == 2) asm volatile("s_waitcnt vmcnt(2)" ::: "memory");
      else              asm volatile("s_waitcnt vmcnt(0)" ::: "memory");
      __builtin_amdgcn_sched_barrier(0);
      __builtin_amdgcn_s_barrier();
    }
  };

  stageA(0, 0, 0);
  stageA(0, 1, 0);
  stageB(0, 0);
  stageA(1, 0, 1);
  stageB(1, 1);
  __builtin_amdgcn_sched_barrier(0);
  asm volatile("s_waitcnt vmcnt(4)" ::: "memory");
  __builtin_amdgcn_sched_barrier(0);
  __builtin_amdgcn_s_barrier();

  for (int t = 0; t < NT_ - 2; ++t) {
    const int cur = t & 1;
    phase0(t, cur, true, 6);
    phase1(t, cur, true, 6);
  }
  phase0(NT_ - 2, (NT_ - 2) & 1, true, 6);
  phase1(NT_ - 2, (NT_ - 2) & 1, false, 2);
  phase0(NT_ - 1, (NT_ - 1) & 1, false, 0);
  phase1(NT_ - 1, (NT_ - 1) & 1, false, -1);

#pragma unroll
  for (int mi = 0; mi < 8; ++mi)
#pragma unroll
    for (int ni = 0; ni < 2; ++ni) {
      const int row = mt * 256 + wm * 128 + mi * 16 + lg * 4;
      const int col = nt * 128 + wn * 32 + ni * 16 + l15;
#pragma unroll
      for (int r = 0; r < 4; ++r)
        Cf[(size_t)(row + r) * DIM_ + col] = acc[mi][ni][r];
    }
}

// ---------- causal flash attention, swapped-QK^T 32x32 structure ----------
#define CEXP 0.12751744f  /* (1/sqrt(128)) * log2(e) */

__global__ __launch_bounds__(256, 2) void attn_kernel(const u16* __restrict__ q,
                                                      const u16* __restrict__ k,
                                                      const u16* __restrict__ v,
                                                      u16* __restrict__ ao) {
  __shared__ __align__(16) u16 smem[17408];
  u16* kTl = smem;
  u16* vTl = smem + 8192;

  const int qt   = blockIdx.z ? (int)blockIdx.x : (int)(gridDim.x - 1 - blockIdx.x);
  const int head = blockIdx.y;
  const int b    = blockIdx.z;
  const int t = threadIdx.x;
  const int lane = t & 63;
  const int w = t >> 6;
  const int l31 = lane & 31;
  const int hi = lane >> 5;
  const int kxor = (lane & 7) << 3;
  const int qrow0 = qt * 128 + w * 32;
  const size_t bS = (size_t)b * S_;

  bf16x8 qf[8];
  {
    const u16* qrow = q + (bS + qrow0 + l31) * DIM_ + head * HD_;
#pragma unroll
    for (int st = 0; st < 8; ++st)
      qf[st] = *(const bf16x8*)(qrow + st * 16 + hi * 8);
  }

  f32x16 accO[4];
#pragma unroll
  for (int db = 0; db < 4; ++db)
#pragma unroll
    for (int r = 0; r < 16; ++r) accO[db][r] = 0.f;
  float m = -1e30f, l = 0.f;

  const int tmax_w = 2 * qt + (w >> 1);
  const int ttend = 2 * qt + 1;

  for (int tt = 0; tt <= ttend; ++tt) {
    __syncthreads();

    bf16x8 vv[4];
#pragma unroll
    for (int p = 0; p < 4; ++p) {
      const int dchunk = p * 4 + w;
      vv[p] = *(const bf16x8*)(v + (bS + tt * 64 + lane) * DIM_ + head * HD_ + dchunk * 8);
    }
#pragma unroll
    for (int p = 0; p < 4; ++p) {
      const int cb = p * 256 + w * 64;
      const int cid = cb + lane;
      const int kr = cid >> 4;
      const int cg = (cid & 15) ^ (kr & 7);
      gload16(k + (bS + tt * 64 + kr) * DIM_ + head * HD_ + cg * 8, kTl + cb * 8);
    }
#pragma unroll
    for (int p = 0; p < 4; ++p) {
      const int dchunk = p * 4 + w;
#pragma unroll
      for (int j = 0; j < 8; ++j) {
        const int d = dchunk * 8 + j;
        vTl[d * 64 + (lane ^ ((d & 7) << 3))] = (u16)vv[p][j];
      }
    }
    __syncthreads();

    if (tt <= tmax_w) {
      f32x16 sA, sB;
#pragma unroll
      for (int r = 0; r < 16; ++r) { sA[r] = 0.f; sB[r] = 0.f; }
      __builtin_amdgcn_s_setprio(1);
#pragma unroll
      for (int st = 0; st < 8; ++st) {
        const int dc = st * 16 + hi * 8;
        bf16x8 k0 = *(const bf16x8*)(kTl + l31 * 128 + (dc ^ kxor));
        bf16x8 k1 = *(const bf16x8*)(kTl + (32 + l31) * 128 + (dc ^ kxor));
        sA = __builtin_amdgcn_mfma_f32_32x32x16_bf16(k0, qf[st], sA, 0, 0, 0);
        sB = __builtin_amdgcn_mfma_f32_32x32x16_bf16(k1, qf[st], sB, 0, 0, 0);
      }
      __builtin_amdgcn_s_setprio(0);

      const int qg = qrow0 + l31;
      if (tt * 64 + 63 > qrow0) {
        const int kb = tt * 64 + 4 * hi;
#pragma unroll
        for (int r = 0; r < 16; ++r) {
          const int kg = kb + (r & 3) + 8 * (r >> 2);
          sA[r] = (kg <= qg) ? sA[r] : -1e30f;
          sB[r] = (kg + 32 <= qg) ? sB[r] : -1e30f;
        }
      }

      float mx[8];
#pragma unroll
      for (int i = 0; i < 8; ++i)
        mx[i] = fmaxf(fmaxf(sA[i], sA[i + 8]), fmaxf(sB[i], sB[i + 8]));
#pragma unroll
      for (int i = 0; i < 4; ++i) mx[i] = fmaxf(mx[i], mx[i + 4]);
      float pm = fmaxf(fmaxf(mx[0], mx[1]), fmaxf(mx[2], mx[3]));
      pm = fmaxf(pm, __shfl_xor(pm, 32));
      const float mN = fmaxf(m, pm);
      if (!__all(pm - m <= 90.5f)) {  // T13 defer-max, THR=8 nat units
        const float osc = exp2f((m - mN) * CEXP);
        l *= osc;
#pragma unroll
        for (int db = 0; db < 4; ++db)
#pragma unroll
          for (int r = 0; r < 16; ++r) accO[db][r] *= osc;
        m = mN;
      }
      const float mc = m * CEXP;
      float lsv[4] = {0.f, 0.f, 0.f, 0.f};
#pragma unroll
      for (int r = 0; r < 16; ++r) {
        const float pa = exp2f(__builtin_fmaf(sA[r], CEXP, -mc));
        const float pb = exp2f(__builtin_fmaf(sB[r], CEXP, -mc));
        sA[r] = pa; sB[r] = pb;
        lsv[r & 3] += pa + pb;
      }
      float ls = (lsv[0] + lsv[1]) + (lsv[2] + lsv[3]);
      ls += __shfl_xor(ls, 32);
      l += ls;

#define PV_STEP(ARR, R0, ST2)                                                      \
      {                                                                            \
        u32 a0 = cvtpk(ARR[(R0) + 0], ARR[(R0) + 1]);                              \
        u32 a1 = cvtpk(ARR[(R0) + 2], ARR[(R0) + 3]);                              \
        u32 b0 = cvtpk(ARR[(R0) + 4], ARR[(R0) + 5]);                              \
        u32 b1 = cvtpk(ARR[(R0) + 6], ARR[(R0) + 7]);                              \
        asm("v_permlane32_swap_b32 %0, %1" : "+v"(a0), "+v"(b0));                  \
        asm("v_permlane32_swap_b32 %0, %1" : "+v"(a1), "+v"(b1));                  \
        union { u32 uu[4]; bf16x8 v8; } pf;                                        \
        pf.uu[0] = a0; pf.uu[1] = a1; pf.uu[2] = b0; pf.uu[3] = b1;                \
        const int ko = (ST2) * 16 + hi * 8;                                        \
        __builtin_amdgcn_s_setprio(1);                                             \
        _Pragma("unroll")                                                          \
        for (int db = 0; db < 4; ++db) {                                           \
          const int dr = db * 32 + l31;                                            \
          bf16x8 vf = *(const bf16x8*)(vTl + dr * 64 + (ko ^ kxor));               \
          accO[db] =                                                               \
              __builtin_amdgcn_mfma_f32_32x32x16_bf16(vf, pf.v8, accO[db], 0, 0, 0); \
        }                                                                          \
        __builtin_amdgcn_s_setprio(0);                                             \
      }
      PV_STEP(sA, 0, 0)
      PV_STEP(sA, 8, 1)
      PV_STEP(sB, 0, 2)
      PV_STEP(sB, 8, 3)
#undef PV_STEP
    }
  }

  __syncthreads();
  const float linv = 1.0f / l;
  u16* oT = smem + w * 4352;
#pragma unroll
  for (int db = 0; db < 4; ++db)
#pragma unroll
    for (int q4 = 0; q4 < 4; ++q4) {
      const int dbase = db * 32 + q4 * 8 + hi * 4;
      const u32 lo = cvtpk(accO[db][q4 * 4 + 0] * linv, accO[db][q4 * 4 + 1] * linv);
      const u32 hiw = cvtpk(accO[db][q4 * 4 + 2] * linv, accO[db][q4 * 4 + 3] * linv);
      *(u32*)(oT + l31 * 136 + dbase) = lo;
      *(u32*)(oT + l31 * 136 + dbase + 2) = hiw;
    }
  __syncthreads();
#pragma unroll
  for (int i = 0; i < 8; ++i) {
    const int cid = i * 64 + lane;
    const int qloc = cid >> 4;
    const int c = cid & 15;
    const bf16x8 val = *(const bf16x8*)(oT + qloc * 136 + c * 8);
    *(bf16x8*)(ao + (bS + qrow0 + qloc) * DIM_ + head * HD_ + c * 8) = val;
  }
}

// ---------- launch ----------
extern "C" void kernel_launch(void* const* d_in, const int* in_sizes, int n_in,
                              void* d_out, int out_size, void* d_ws, size_t ws_size,
                              hipStream_t stream) {
  const float* x  = (const float*)d_in[0];
  const float* wq = (const float*)d_in[2];
  const float* wk = (const float*)d_in[3];
  const float* wv = (const float*)d_in[4];
  const float* wo = (const float*)d_in[5];

  char* ws = (char*)d_ws;
  size_t off = 0;
  auto carve = [&](size_t bytes) { char* p = ws + off; off += bytes; return p; };
  u16* xb   = (u16*)carve((size_t)M_ * DIM_ * 2);
  u16* wqb  = (u16*)carve((size_t)DIM_ * DIM_ * 2);
  u16* wkb  = (u16*)carve((size_t)DIM_ * DIM_ * 2);
  u16* wvb  = (u16*)carve((size_t)DIM_ * DIM_ * 2);
  u16* wob  = (u16*)carve((size_t)DIM_ * DIM_ * 2);
  u16* qb   = (u16*)carve((size_t)M_ * DIM_ * 2);
  u16* kb   = (u16*)carve((size_t)M_ * DIM_ * 2);
  u16* vb   = (u16*)carve((size_t)M_ * DIM_ * 2);
  u16* aob  = (u16*)carve((size_t)M_ * DIM_ * 2);
  float* cosT = (float*)carve((size_t)S_ * 64 * 4);
  float* sinT = (float*)carve((size_t)S_ * 64 * 4);
  if (off > ws_size) return;

  dim3 gc(1024, 5);
  convert5_kernel<<<gc, 256, 0, stream>>>(x, wq, wk, wv, wo, xb, wqb, wkb, wvb, wob);
  rope_table_kernel<<<512, 256, 0, stream>>>(cosT, sinT);

  gemm256_qkv_kernel<<<384, 512, 0, stream>>>(xb, wqb, wkb, wvb, qb, kb, vb);

  dim3 gr((B_ * S_ * H_ * 64) / 256, 2);
  rope_apply_kernel<<<gr, 256, 0, stream>>>(qb, kb, cosT, sinT);

  dim3 ga(S_ / 128, H_, B_);
  attn_kernel<<<ga, 256, 0, stream>>>(qb, kb, vb, aob);

  gemm8_out_kernel<<<256, 512, 0, stream>>>(aob, wob, (float*)d_out);
}

// Round 7
// 285.433 us; speedup vs baseline: 1.0031x; 1.0031x over previous
//
#include <hip/hip_runtime.h>
#include <cstdint>

typedef unsigned short u16;
typedef uint32_t u32;
typedef __attribute__((ext_vector_type(8))) short bf16x8;
typedef __attribute__((ext_vector_type(4))) float f32x4;
typedef __attribute__((ext_vector_type(16))) float f32x16;

#define DIM_ 2048
#define S_   2048
#define B_   2
#define H_   16
#define HD_  128
#define M_   (B_ * S_)  // 4096

// ---------- scalar bf16 helpers (RNE) ----------
__device__ __forceinline__ u16 f2b(float f) {
  union { float f; uint32_t u; } v; v.f = f;
  uint32_t u = v.u;
  return (u16)((u + 0x7FFFu + ((u >> 16) & 1u)) >> 16);
}
__device__ __forceinline__ float b2f(u16 h) {
  union { uint32_t u; float f; } v; v.u = ((uint32_t)h) << 16;
  return v.f;
}

__device__ __forceinline__ u32 cvtpk(float lo, float hi) {
  u32 r;
  asm("v_cvt_pk_bf16_f32 %0, %1, %2" : "=v"(r) : "v"(lo), "v"(hi));
  return r;
}

// ---------- global -> LDS async copy (16B per lane, wave-uniform LDS base) ----------
typedef __attribute__((address_space(3))) u16 lds_u16_t;
typedef __attribute__((address_space(1))) const u16 glob_u16_t;

__device__ __forceinline__ void gload16(const u16* g, u16* l) {
  __builtin_amdgcn_global_load_lds((glob_u16_t*)g, (lds_u16_t*)l, 16, 0, 0);
}
#define GLD0(SRC, DST) \
  __builtin_amdgcn_global_load_lds((glob_u16_t*)(SRC), (lds_u16_t*)(DST), 16, 0, 0)

// ---------- fp32 -> bf16 convert, 5 buffers in one launch ----------
__global__ void convert5_kernel(const float* __restrict__ x, const float* __restrict__ wq,
                                const float* __restrict__ wk, const float* __restrict__ wv,
                                const float* __restrict__ wo, u16* __restrict__ xb,
                                u16* __restrict__ wqb, u16* __restrict__ wkb,
                                u16* __restrict__ wvb, u16* __restrict__ wob) {
  const float* src;
  u16* dst;
  int n;
  switch (blockIdx.y) {
    case 0: src = x;  dst = xb;  n = M_ * DIM_;   break;
    case 1: src = wq; dst = wqb; n = DIM_ * DIM_; break;
    case 2: src = wk; dst = wkb; n = DIM_ * DIM_; break;
    case 3: src = wv; dst = wvb; n = DIM_ * DIM_; break;
    default: src = wo; dst = wob; n = DIM_ * DIM_; break;
  }
  int i = (blockIdx.x * blockDim.x + threadIdx.x) * 4;
  const int stride = gridDim.x * blockDim.x * 4;
  for (; i < n; i += stride) {
    float4 v = *reinterpret_cast<const float4*>(src + i);
    uint64_t p = (uint64_t)f2b(v.x) | ((uint64_t)f2b(v.y) << 16) |
                 ((uint64_t)f2b(v.z) << 32) | ((uint64_t)f2b(v.w) << 48);
    *reinterpret_cast<uint64_t*>(dst + i) = p;
  }
}

// ---------- RoPE tables: cos/sin [S][64] fp32 ----------
__global__ void rope_table_kernel(float* __restrict__ cosT, float* __restrict__ sinT) {
  int i = blockIdx.x * blockDim.x + threadIdx.x;
  if (i >= S_ * 64) return;
  int s = i >> 6, d = i & 63;
  float inv = powf(10000.0f, -(float)d * (1.0f / 64.0f));
  float ang = (float)s * inv;
  cosT[i] = cosf(ang);
  sinT[i] = sinf(ang);
}

// ---------- RoPE apply (in-place, rotate-half, D=128), q and k in one launch ----------
__global__ void rope_apply_kernel(u16* __restrict__ qb, u16* __restrict__ kb,
                                  const float* __restrict__ cosT,
                                  const float* __restrict__ sinT) {
  u16* buf = blockIdx.y ? kb : qb;
  int i = blockIdx.x * blockDim.x + threadIdx.x;  // over B*S*H*64
  if (i >= B_ * S_ * H_ * 64) return;
  int d = i & 63;
  int h = (i >> 6) & (H_ - 1);
  int row = i >> 10;        // b*S + s
  int s = row & (S_ - 1);
  u16* p = buf + (size_t)row * DIM_ + h * HD_ + d;
  float t1 = b2f(p[0]);
  float t2 = b2f(p[64]);
  float c = cosT[s * 64 + d];
  float sn = sinT[s * 64 + d];
  p[0]  = f2b(t1 * c - t2 * sn);
  p[64] = f2b(t2 * c + t1 * sn);
}

// ==================================================================================
// GEMM v2: 2-phase k-slice schedule with one-phase register lookahead.
// Tile BM=256 x BN (256 QKV / 128 O), BK=64, 512 thr = 8 waves (2M x 4N).
// Phase = k-slot (32 independent MFMA, no acc chains). Per tile t (buf=cur):
//  PhaseA: issue R1 = {a1,b1} (ks1, cur)          -> drains under MFMA ks0
//          MFMA ks0 (a0,b0; compiler lgkm-waits R3(t-1))
//  PhaseB: lgkmcnt(0)  [all reads of cur done, incl. R1]  ; s_barrier B1
//          STAGE full tile t+2 -> cur (linear rows; cur is fully consumed)
//          vmcnt(NLD)  [t+1's loads landed; t+2's in flight] ; s_barrier B2
//          issue R3 = {a0,b0} (ks0, buf^1 = t+1) -> drains under MFMA ks1
//          MFMA ks1 (a1,b1; no wait needed)
// 2 barriers/tile. LDS 2 bufs x [A 256x64 | B BNx64], chunk-XOR swizzle (c ^= row&7)
// staged via inverse-swizzled global source (rule 21).
// ==================================================================================
#define NT_ 32  // 2048 / 64

// --- macros parameterized by function-local constexprs: NF_, BUFSZ_, ASW_, BSW_ ---
#define LDA(DST, BASE)                                                         \
  _Pragma("unroll") for (int mi = 0; mi < 8; ++mi)                             \
      DST[mi] = *(const bf16x8*)((BASE) + mi * 1024);
#define LDB(DST, BASE)                                                         \
  _Pragma("unroll") for (int ni = 0; ni < NF_; ++ni)                           \
      DST[ni] = *(const bf16x8*)((BASE) + ni * 1024);

#define MFMA_KS(AV, BV)                                                        \
  _Pragma("unroll") for (int mi = 0; mi < 8; ++mi)                             \
    _Pragma("unroll") for (int ni = 0; ni < NF_; ++ni)                         \
        acc[mi][ni] = __builtin_amdgcn_mfma_f32_16x16x32_bf16(                 \
            AV[mi], BV[ni], acc[mi][ni], 0, 0, 0);

#define STAGE(BUF, OFFU) do {                                                  \
    _Pragma("unroll") for (int s = 0; s < ASW_; ++s)                           \
      GLD0(sA + goff + (OFFU) + s * (64 * DIM_),                               \
           lds + (BUF) * BUFSZ_ + s * 4096 + w * 512);                         \
    _Pragma("unroll") for (int s = 0; s < BSW_; ++s)                           \
      GLD0(sB + goff + (OFFU) + s * (64 * DIM_),                               \
           lds + (BUF) * BUFSZ_ + 16384 + s * 4096 + w * 512);                 \
  } while (0)

#define VMC_N() do {                                                           \
    if (ASW_ + BSW_ == 8) asm volatile("s_waitcnt vmcnt(8)" ::: "memory");     \
    else                  asm volatile("s_waitcnt vmcnt(6)" ::: "memory");     \
  } while (0)

#define TILE_N(BUF, NBUF, OFFU) do {                                           \
    LDA(a1, pAk1[BUF]); LDB(b1, pBk1[BUF]);              /* R1 */              \
    __builtin_amdgcn_sched_barrier(0);                                         \
    __builtin_amdgcn_s_setprio(1);                                             \
    MFMA_KS(a0, b0);                                     /* ks0 */             \
    __builtin_amdgcn_s_setprio(0);                                             \
    asm volatile("s_waitcnt lgkmcnt(0)" ::: "memory");                         \
    __builtin_amdgcn_sched_barrier(0);                                         \
    __builtin_amdgcn_s_barrier();                        /* B1 */              \
    STAGE(BUF, OFFU);                                                          \
    __builtin_amdgcn_sched_barrier(0);                                         \
    VMC_N();                                                                   \
    __builtin_amdgcn_sched_barrier(0);                                         \
    __builtin_amdgcn_s_barrier();                        /* B2 */              \
    LDA(a0, pAk0[NBUF]); LDB(b0, pBk0[NBUF]);            /* R3 */              \
    __builtin_amdgcn_sched_barrier(0);                                         \
    __builtin_amdgcn_s_setprio(1);                                             \
    MFMA_KS(a1, b1);                                     /* ks1 */             \
    __builtin_amdgcn_s_setprio(0);                                             \
  } while (0)

#define TILE_P(BUF, NBUF) do {                           /* t = NT-2 */        \
    LDA(a1, pAk1[BUF]); LDB(b1, pBk1[BUF]);                                    \
    __builtin_amdgcn_sched_barrier(0);                                         \
    __builtin_amdgcn_s_setprio(1);                                             \
    MFMA_KS(a0, b0);                                                           \
    __builtin_amdgcn_s_setprio(0);                                             \
    asm volatile("s_waitcnt lgkmcnt(0)" ::: "memory");                         \
    __builtin_amdgcn_sched_barrier(0);                                         \
    asm volatile("s_waitcnt vmcnt(0)" ::: "memory");                           \
    __builtin_amdgcn_sched_barrier(0);                                         \
    __builtin_amdgcn_s_barrier();                                              \
    LDA(a0, pAk0[NBUF]); LDB(b0, pBk0[NBUF]);                                  \
    __builtin_amdgcn_sched_barrier(0);                                         \
    __builtin_amdgcn_s_setprio(1);                                             \
    MFMA_KS(a1, b1);                                                           \
    __builtin_amdgcn_s_setprio(0);                                             \
  } while (0)

#define TILE_L(BUF) do {                                 /* t = NT-1 */        \
    LDA(a1, pAk1[BUF]); LDB(b1, pBk1[BUF]);                                    \
    __builtin_amdgcn_sched_barrier(0);                                         \
    MFMA_KS(a0, b0);                                                           \
    MFMA_KS(a1, b1);                                                           \
  } while (0)

#define GEMM_V2_BODY(BN_)                                                      \
  constexpr int NF_ = (BN_) / 64;       /* b frags per ks per wave */          \
  constexpr int ASW_ = 4;               /* A stage sweeps (64 rows each) */    \
  constexpr int BSW_ = (BN_) / 64;      /* B stage sweeps */                   \
  constexpr int BUFSZ_ = 16384 + (BN_) * 64; /* u16 per buffer */              \
  const int tid = threadIdx.x;                                                 \
  const int lane = tid & 63;                                                   \
  const int w = tid >> 6;                                                      \
  const int wm = w >> 2, wn = w & 3;                                           \
  const int l15 = lane & 15, lg = lane >> 4;                                   \
  /* per-lane global stage offset: row = w*8 + lane>>3, inv-swizzled chunk */  \
  const int goff = (w * 8 + (lane >> 3)) * DIM_ + ((lane & 7) ^ (lane >> 3)) * 8; \
  /* LDS read bases: row*64 + ((ks*4+lg)^ (l15&7))*8, row = l15 + frag*16 */   \
  const int x7 = l15 & 7;                                                      \
  const int lr0 = l15 * 64 + ((lg ^ x7) * 8);                                  \
  const int lr1 = l15 * 64 + (((4 | lg) ^ x7) * 8);                            \
  const u16* pAk0[2] = {lds + wm * 8192 + lr0, lds + BUFSZ_ + wm * 8192 + lr0};\
  const u16* pAk1[2] = {lds + wm * 8192 + lr1, lds + BUFSZ_ + wm * 8192 + lr1};\
  const u16* pBk0[2] = {lds + 16384 + wn * ((BN_)*16) + lr0,                   \
                        lds + BUFSZ_ + 16384 + wn * ((BN_)*16) + lr0};         \
  const u16* pBk1[2] = {lds + 16384 + wn * ((BN_)*16) + lr1,                   \
                        lds + BUFSZ_ + 16384 + wn * ((BN_)*16) + lr1};         \
  f32x4 acc[8][NF_];                                                           \
  _Pragma("unroll") for (int i = 0; i < 8; ++i)                                \
    _Pragma("unroll") for (int j = 0; j < NF_; ++j)                            \
        acc[i][j] = (f32x4){0.f, 0.f, 0.f, 0.f};                               \
  bf16x8 a0[8], a1[8], b0[NF_], b1[NF_];                                       \
  /* prologue: stage t0->buf0, t1->buf1; land t0; preload ks0(t0) */           \
  STAGE(0, 0);                                                                 \
  STAGE(1, 64);                                                                \
  __builtin_amdgcn_sched_barrier(0);                                           \
  VMC_N();                                                                     \
  __builtin_amdgcn_sched_barrier(0);                                           \
  __builtin_amdgcn_s_barrier();                                                \
  LDA(a0, pAk0[0]); LDB(b0, pBk0[0]);                                          \
  for (int t = 0; t < NT_ - 2; t += 2) {                                       \
    TILE_N(0, 1, 128);                                                         \
    TILE_N(1, 0, 192);                                                         \
    sA += 128; sB += 128;                                                      \
  }                                                                            \
  TILE_P(0, 1);                                                                \
  TILE_L(1);

// ---------------- QKV: BN=256, 384 blocks, bf16 out ----------------
__global__ __launch_bounds__(512, 2) void gemm256_qkv_kernel(
    const u16* __restrict__ xb, const u16* __restrict__ wqb, const u16* __restrict__ wkb,
    const u16* __restrict__ wvb, u16* __restrict__ qb, u16* __restrict__ kb,
    u16* __restrict__ vb) {
  __shared__ __align__(16) u16 lds[65536];  // 128 KB

  // XCD swizzle (384 % 8 == 0) + A-panel grouping: logical = mt*24 + z*8 + nt
  const int bid = blockIdx.x;
  const int logical = (bid & 7) * 48 + (bid >> 3);
  const int mt = logical / 24;
  const int rem = logical % 24;
  const int z = rem >> 3;
  const int nt = rem & 7;
  const u16* Wm = (z == 0) ? wqb : (z == 1) ? wkb : wvb;
  u16* out = (z == 0) ? qb : (z == 1) ? kb : vb;

  const u16* sA = xb + (size_t)(mt * 256) * DIM_;
  const u16* sB = Wm + (size_t)(nt * 256) * DIM_;

  GEMM_V2_BODY(256)

  // epilogue: D layout row=(lane>>4)*4+r, col=lane&15 per 16x16 frag
#pragma unroll
  for (int mi = 0; mi < 8; ++mi)
#pragma unroll
    for (int ni = 0; ni < 4; ++ni) {
      const int row = mt * 256 + wm * 128 + mi * 16 + lg * 4;
      const int col = nt * 256 + wn * 64 + ni * 16 + l15;
#pragma unroll
      for (int r = 0; r < 4; ++r)
        out[(size_t)(row + r) * DIM_ + col] = f2b(acc[mi][ni][r]);
    }
}

// ---------------- O-projection: BN=128, 256 blocks = 1 exact round, f32 out ----------------
__global__ __launch_bounds__(512, 2) void gemm_out_v2_kernel(const u16* __restrict__ A,
                                                             const u16* __restrict__ W,
                                                             float* __restrict__ Cf) {
  __shared__ __align__(16) u16 lds[49152];  // 96 KB
  const int bid = blockIdx.x;
  const int logical = (bid & 7) * 32 + (bid >> 3);
  const int mt = logical >> 4;
  const int nt = logical & 15;

  const u16* sA = A + (size_t)(mt * 256) * DIM_;
  const u16* sB = W + (size_t)(nt * 128) * DIM_;

  GEMM_V2_BODY(128)

#pragma unroll
  for (int mi = 0; mi < 8; ++mi)
#pragma unroll
    for (int ni = 0; ni < 2; ++ni) {
      const int row = mt * 256 + wm * 128 + mi * 16 + lg * 4;
      const int col = nt * 128 + wn * 32 + ni * 16 + l15;
#pragma unroll
      for (int r = 0; r < 4; ++r)
        Cf[(size_t)(row + r) * DIM_ + col] = acc[mi][ni][r];
    }
}

// ---------- causal flash attention, swapped-QK^T 32x32 structure (unchanged) ----------
#define CEXP 0.12751744f  /* (1/sqrt(128)) * log2(e) */

__global__ __launch_bounds__(256, 2) void attn_kernel(const u16* __restrict__ q,
                                                      const u16* __restrict__ k,
                                                      const u16* __restrict__ v,
                                                      u16* __restrict__ ao) {
  __shared__ __align__(16) u16 smem[17408];
  u16* kTl = smem;
  u16* vTl = smem + 8192;

  const int qt   = blockIdx.z ? (int)blockIdx.x : (int)(gridDim.x - 1 - blockIdx.x);
  const int head = blockIdx.y;
  const int b    = blockIdx.z;
  const int t = threadIdx.x;
  const int lane = t & 63;
  const int w = t >> 6;
  const int l31 = lane & 31;
  const int hi = lane >> 5;
  const int kxor = (lane & 7) << 3;
  const int qrow0 = qt * 128 + w * 32;
  const size_t bS = (size_t)b * S_;

  bf16x8 qf[8];
  {
    const u16* qrow = q + (bS + qrow0 + l31) * DIM_ + head * HD_;
#pragma unroll
    for (int st = 0; st < 8; ++st)
      qf[st] = *(const bf16x8*)(qrow + st * 16 + hi * 8);
  }

  f32x16 accO[4];
#pragma unroll
  for (int db = 0; db < 4; ++db)
#pragma unroll
    for (int r = 0; r < 16; ++r) accO[db][r] = 0.f;
  float m = -1e30f, l = 0.f;

  const int tmax_w = 2 * qt + (w >> 1);
  const int ttend = 2 * qt + 1;

  for (int tt = 0; tt <= ttend; ++tt) {
    __syncthreads();

    bf16x8 vv[4];
#pragma unroll
    for (int p = 0; p < 4; ++p) {
      const int dchunk = p * 4 + w;
      vv[p] = *(const bf16x8*)(v + (bS + tt * 64 + lane) * DIM_ + head * HD_ + dchunk * 8);
    }
#pragma unroll
    for (int p = 0; p < 4; ++p) {
      const int cb = p * 256 + t;
      const int cid = p * 256 + w * 64 + lane;
      const int kr = cid >> 4;
      const int cg = (cid & 15) ^ (kr & 7);
      gload16(k + (bS + tt * 64 + kr) * DIM_ + head * HD_ + cg * 8,
              kTl + (p * 256 + w * 64) * 8);
    }
#pragma unroll
    for (int p = 0; p < 4; ++p) {
      const int dchunk = p * 4 + w;
#pragma unroll
      for (int j = 0; j < 8; ++j) {
        const int d = dchunk * 8 + j;
        vTl[d * 64 + (lane ^ ((d & 7) << 3))] = (u16)vv[p][j];
      }
    }
    __syncthreads();

    if (tt <= tmax_w) {
      f32x16 sA, sB;
#pragma unroll
      for (int r = 0; r < 16; ++r) { sA[r] = 0.f; sB[r] = 0.f; }
      __builtin_amdgcn_s_setprio(1);
#pragma unroll
      for (int st = 0; st < 8; ++st) {
        const int dc = st * 16 + hi * 8;
        bf16x8 k0 = *(const bf16x8*)(kTl + l31 * 128 + (dc ^ kxor));
        bf16x8 k1 = *(const bf16x8*)(kTl + (32 + l31) * 128 + (dc ^ kxor));
        sA = __builtin_amdgcn_mfma_f32_32x32x16_bf16(k0, qf[st], sA, 0, 0, 0);
        sB = __builtin_amdgcn_mfma_f32_32x32x16_bf16(k1, qf[st], sB, 0, 0, 0);
      }
      __builtin_amdgcn_s_setprio(0);

      const int qg = qrow0 + l31;
      if (tt * 64 + 63 > qrow0) {
        const int kb = tt * 64 + 4 * hi;
#pragma unroll
        for (int r = 0; r < 16; ++r) {
          const int kg = kb + (r & 3) + 8 * (r >> 2);
          sA[r] = (kg <= qg) ? sA[r] : -1e30f;
          sB[r] = (kg + 32 <= qg) ? sB[r] : -1e30f;
        }
      }

      float mx[8];
#pragma unroll
      for (int i = 0; i < 8; ++i)
        mx[i] = fmaxf(fmaxf(sA[i], sA[i + 8]), fmaxf(sB[i], sB[i + 8]));
#pragma unroll
      for (int i = 0; i < 4; ++i) mx[i] = fmaxf(mx[i], mx[i + 4]);
      float pm = fmaxf(fmaxf(mx[0], mx[1]), fmaxf(mx[2], mx[3]));
      pm = fmaxf(pm, __shfl_xor(pm, 32));
      const float mN = fmaxf(m, pm);
      if (!__all(pm - m <= 90.5f)) {  // T13 defer-max
        const float osc = exp2f((m - mN) * CEXP);
        l *= osc;
#pragma unroll
        for (int db = 0; db < 4; ++db)
#pragma unroll
          for (int r = 0; r < 16; ++r) accO[db][r] *= osc;
        m = mN;
      }
      const float mc = m * CEXP;
      float lsv[4] = {0.f, 0.f, 0.f, 0.f};
#pragma unroll
      for (int r = 0; r < 16; ++r) {
        const float pa = exp2f(__builtin_fmaf(sA[r], CEXP, -mc));
        const float pb = exp2f(__builtin_fmaf(sB[r], CEXP, -mc));
        sA[r] = pa; sB[r] = pb;
        lsv[r & 3] += pa + pb;
      }
      float ls = (lsv[0] + lsv[1]) + (lsv[2] + lsv[3]);
      ls += __shfl_xor(ls, 32);
      l += ls;

#define PV_STEP(ARR, R0, ST2)                                                      \
      {                                                                            \
        u32 a0 = cvtpk(ARR[(R0) + 0], ARR[(R0) + 1]);                              \
        u32 a1 = cvtpk(ARR[(R0) + 2], ARR[(R0) + 3]);                              \
        u32 b0 = cvtpk(ARR[(R0) + 4], ARR[(R0) + 5]);                              \
        u32 b1 = cvtpk(ARR[(R0) + 6], ARR[(R0) + 7]);                              \
        asm("v_permlane32_swap_b32 %0, %1" : "+v"(a0), "+v"(b0));                  \
        asm("v_permlane32_swap_b32 %0, %1" : "+v"(a1), "+v"(b1));                  \
        union { u32 uu[4]; bf16x8 v8; } pf;                                        \
        pf.uu[0] = a0; pf.uu[1] = a1; pf.uu[2] = b0; pf.uu[3] = b1;                \
        const int ko = (ST2) * 16 + hi * 8;                                        \
        __builtin_amdgcn_s_setprio(1);                                             \
        _Pragma("unroll")                                                          \
        for (int db = 0; db < 4; ++db) {                                           \
          const int dr = db * 32 + l31;                                            \
          bf16x8 vf = *(const bf16x8*)(vTl + dr * 64 + (ko ^ kxor));               \
          accO[db] =                                                               \
              __builtin_amdgcn_mfma_f32_32x32x16_bf16(vf, pf.v8, accO[db], 0, 0, 0); \
        }                                                                          \
        __builtin_amdgcn_s_setprio(0);                                             \
      }
      PV_STEP(sA, 0, 0)
      PV_STEP(sA, 8, 1)
      PV_STEP(sB, 0, 2)
      PV_STEP(sB, 8, 3)
#undef PV_STEP
    }
  }

  __syncthreads();
  const float linv = 1.0f / l;
  u16* oT = smem + w * 4352;
#pragma unroll
  for (int db = 0; db < 4; ++db)
#pragma unroll
    for (int q4 = 0; q4 < 4; ++q4) {
      const int dbase = db * 32 + q4 * 8 + hi * 4;
      const u32 lo = cvtpk(accO[db][q4 * 4 + 0] * linv, accO[db][q4 * 4 + 1] * linv);
      const u32 hiw = cvtpk(accO[db][q4 * 4 + 2] * linv, accO[db][q4 * 4 + 3] * linv);
      *(u32*)(oT + l31 * 136 + dbase) = lo;
      *(u32*)(oT + l31 * 136 + dbase + 2) = hiw;
    }
  __syncthreads();
#pragma unroll
  for (int i = 0; i < 8; ++i) {
    const int cid = i * 64 + lane;
    const int qloc = cid >> 4;
    const int c = cid & 15;
    const bf16x8 val = *(const bf16x8*)(oT + qloc * 136 + c * 8);
    *(bf16x8*)(ao + (bS + qrow0 + qloc) * DIM_ + head * HD_ + c * 8) = val;
  }
}

// ---------- launch ----------
extern "C" void kernel_launch(void* const* d_in, const int* in_sizes, int n_in,
                              void* d_out, int out_size, void* d_ws, size_t ws_size,
                              hipStream_t stream) {
  const float* x  = (const float*)d_in[0];
  const float* wq = (const float*)d_in[2];
  const float* wk = (const float*)d_in[3];
  const float* wv = (const float*)d_in[4];
  const float* wo = (const float*)d_in[5];

  char* ws = (char*)d_ws;
  size_t off = 0;
  auto carve = [&](size_t bytes) { char* p = ws + off; off += bytes; return p; };
  u16* xb   = (u16*)carve((size_t)M_ * DIM_ * 2);
  u16* wqb  = (u16*)carve((size_t)DIM_ * DIM_ * 2);
  u16* wkb  = (u16*)carve((size_t)DIM_ * DIM_ * 2);
  u16* wvb  = (u16*)carve((size_t)DIM_ * DIM_ * 2);
  u16* wob  = (u16*)carve((size_t)DIM_ * DIM_ * 2);
  u16* qb   = (u16*)carve((size_t)M_ * DIM_ * 2);
  u16* kb   = (u16*)carve((size_t)M_ * DIM_ * 2);
  u16* vb   = (u16*)carve((size_t)M_ * DIM_ * 2);
  u16* aob  = (u16*)carve((size_t)M_ * DIM_ * 2);
  float* cosT = (float*)carve((size_t)S_ * 64 * 4);
  float* sinT = (float*)carve((size_t)S_ * 64 * 4);
  if (off > ws_size) return;

  dim3 gc(1024, 5);
  convert5_kernel<<<gc, 256, 0, stream>>>(x, wq, wk, wv, wo, xb, wqb, wkb, wvb, wob);
  rope_table_kernel<<<512, 256, 0, stream>>>(cosT, sinT);

  gemm256_qkv_kernel<<<384, 512, 0, stream>>>(xb, wqb, wkb, wvb, qb, kb, vb);

  dim3 gr((B_ * S_ * H_ * 64) / 256, 2);
  rope_apply_kernel<<<gr, 256, 0, stream>>>(qb, kb, cosT, sinT);

  dim3 ga(S_ / 128, H_, B_);
  attn_kernel<<<ga, 256, 0, stream>>>(qb, kb, vb, aob);

  gemm_out_v2_kernel<<<256, 512, 0, stream>>>(aob, wob, (float*)d_out);
}

// Round 8
// 277.926 us; speedup vs baseline: 1.0302x; 1.0270x over previous
//
#include <hip/hip_runtime.h>
#include <cstdint>

typedef unsigned short u16;
typedef uint32_t u32;
typedef __attribute__((ext_vector_type(8))) short bf16x8;
typedef __attribute__((ext_vector_type(4))) float f32x4;
typedef __attribute__((ext_vector_type(16))) float f32x16;

#define DIM_ 2048
#define S_   2048
#define B_   2
#define H_   16
#define HD_  128
#define M_   (B_ * S_)  // 4096

// ---------- scalar bf16 helpers (RNE) ----------
__device__ __forceinline__ u16 f2b(float f) {
  union { float f; uint32_t u; } v; v.f = f;
  uint32_t u = v.u;
  return (u16)((u + 0x7FFFu + ((u >> 16) & 1u)) >> 16);
}
__device__ __forceinline__ float b2f(u16 h) {
  union { uint32_t u; float f; } v; v.u = ((uint32_t)h) << 16;
  return v.f;
}

__device__ __forceinline__ u32 cvtpk(float lo, float hi) {
  u32 r;
  asm("v_cvt_pk_bf16_f32 %0, %1, %2" : "=v"(r) : "v"(lo), "v"(hi));
  return r;
}

// ---------- global -> LDS async copy (16B per lane, wave-uniform LDS base) ----------
typedef __attribute__((address_space(3))) u16 lds_u16_t;
typedef __attribute__((address_space(1))) const u16 glob_u16_t;

__device__ __forceinline__ void gload16(const u16* g, u16* l) {
  __builtin_amdgcn_global_load_lds((glob_u16_t*)g, (lds_u16_t*)l, 16, 0, 0);
}
#define GLD0(SRC, DST) \
  __builtin_amdgcn_global_load_lds((glob_u16_t*)(SRC), (lds_u16_t*)(DST), 16, 0, 0)

// ---------- fp32 -> bf16 convert, 5 buffers in one launch ----------
__global__ void convert5_kernel(const float* __restrict__ x, const float* __restrict__ wq,
                                const float* __restrict__ wk, const float* __restrict__ wv,
                                const float* __restrict__ wo, u16* __restrict__ xb,
                                u16* __restrict__ wqb, u16* __restrict__ wkb,
                                u16* __restrict__ wvb, u16* __restrict__ wob) {
  const float* src;
  u16* dst;
  int n;
  switch (blockIdx.y) {
    case 0: src = x;  dst = xb;  n = M_ * DIM_;   break;
    case 1: src = wq; dst = wqb; n = DIM_ * DIM_; break;
    case 2: src = wk; dst = wkb; n = DIM_ * DIM_; break;
    case 3: src = wv; dst = wvb; n = DIM_ * DIM_; break;
    default: src = wo; dst = wob; n = DIM_ * DIM_; break;
  }
  int i = (blockIdx.x * blockDim.x + threadIdx.x) * 4;
  const int stride = gridDim.x * blockDim.x * 4;
  for (; i < n; i += stride) {
    float4 v = *reinterpret_cast<const float4*>(src + i);
    uint64_t p = (uint64_t)f2b(v.x) | ((uint64_t)f2b(v.y) << 16) |
                 ((uint64_t)f2b(v.z) << 32) | ((uint64_t)f2b(v.w) << 48);
    *reinterpret_cast<uint64_t*>(dst + i) = p;
  }
}

// ---------- RoPE tables: cos/sin [S][64] fp32 ----------
__global__ void rope_table_kernel(float* __restrict__ cosT, float* __restrict__ sinT) {
  int i = blockIdx.x * blockDim.x + threadIdx.x;
  if (i >= S_ * 64) return;
  int s = i >> 6, d = i & 63;
  float inv = powf(10000.0f, -(float)d * (1.0f / 64.0f));
  float ang = (float)s * inv;
  cosT[i] = cosf(ang);
  sinT[i] = sinf(ang);
}

// ---------- RoPE apply, vectorized x8 (in-place, rotate-half, D=128) ----------
__global__ void rope_apply_kernel(u16* __restrict__ qb, u16* __restrict__ kb,
                                  const float* __restrict__ cosT,
                                  const float* __restrict__ sinT) {
  u16* buf = blockIdx.y ? kb : qb;
  int i = blockIdx.x * blockDim.x + threadIdx.x;  // over B*S*H*8 (8 d's per thread)
  if (i >= B_ * S_ * H_ * 8) return;
  const int c8 = i & 7;              // 8-elem chunk within lower half (d = c8*8..c8*8+7)
  const int h = (i >> 3) & (H_ - 1);
  const int row = i >> 7;            // b*S + s
  const int s = row & (S_ - 1);
  u16* p = buf + (size_t)row * DIM_ + h * HD_ + c8 * 8;
  bf16x8 t1v = *(bf16x8*)p;
  bf16x8 t2v = *(bf16x8*)(p + 64);
  const float4 c0 = *(const float4*)(cosT + s * 64 + c8 * 8);
  const float4 c1 = *(const float4*)(cosT + s * 64 + c8 * 8 + 4);
  const float4 s0 = *(const float4*)(sinT + s * 64 + c8 * 8);
  const float4 s1 = *(const float4*)(sinT + s * 64 + c8 * 8 + 4);
  const float cc[8] = {c0.x, c0.y, c0.z, c0.w, c1.x, c1.y, c1.z, c1.w};
  const float ss[8] = {s0.x, s0.y, s0.z, s0.w, s1.x, s1.y, s1.z, s1.w};
  bf16x8 o1, o2;
#pragma unroll
  for (int j = 0; j < 8; ++j) {
    const float t1 = b2f((u16)t1v[j]);
    const float t2 = b2f((u16)t2v[j]);
    o1[j] = (short)f2b(t1 * cc[j] - t2 * ss[j]);
    o2[j] = (short)f2b(t2 * cc[j] + t1 * ss[j]);
  }
  *(bf16x8*)p = o1;
  *(bf16x8*)(p + 64) = o2;
}

// ==================================================================================
// GEMM v2 (unchanged from R7): 2-phase k-slice schedule with one-phase reg lookahead.
// ==================================================================================
#define NT_ 32  // 2048 / 64

#define LDA(DST, BASE)                                                         \
  _Pragma("unroll") for (int mi = 0; mi < 8; ++mi)                             \
      DST[mi] = *(const bf16x8*)((BASE) + mi * 1024);
#define LDB(DST, BASE)                                                         \
  _Pragma("unroll") for (int ni = 0; ni < NF_; ++ni)                           \
      DST[ni] = *(const bf16x8*)((BASE) + ni * 1024);

#define MFMA_KS(AV, BV)                                                        \
  _Pragma("unroll") for (int mi = 0; mi < 8; ++mi)                             \
    _Pragma("unroll") for (int ni = 0; ni < NF_; ++ni)                         \
        acc[mi][ni] = __builtin_amdgcn_mfma_f32_16x16x32_bf16(                 \
            AV[mi], BV[ni], acc[mi][ni], 0, 0, 0);

#define STAGE(BUF, OFFU) do {                                                  \
    _Pragma("unroll") for (int s = 0; s < ASW_; ++s)                           \
      GLD0(sA + goff + (OFFU) + s * (64 * DIM_),                               \
           lds + (BUF) * BUFSZ_ + s * 4096 + w * 512);                         \
    _Pragma("unroll") for (int s = 0; s < BSW_; ++s)                           \
      GLD0(sB + goff + (OFFU) + s * (64 * DIM_),                               \
           lds + (BUF) * BUFSZ_ + 16384 + s * 4096 + w * 512);                 \
  } while (0)

#define VMC_N() do {                                                           \
    if (ASW_ + BSW_ == 8) asm volatile("s_waitcnt vmcnt(8)" ::: "memory");     \
    else                  asm volatile("s_waitcnt vmcnt(6)" ::: "memory");     \
  } while (0)

#define TILE_N(BUF, NBUF, OFFU) do {                                           \
    LDA(a1, pAk1[BUF]); LDB(b1, pBk1[BUF]);              /* R1 */              \
    __builtin_amdgcn_sched_barrier(0);                                         \
    __builtin_amdgcn_s_setprio(1);                                             \
    MFMA_KS(a0, b0);                                     /* ks0 */             \
    __builtin_amdgcn_s_setprio(0);                                             \
    asm volatile("s_waitcnt lgkmcnt(0)" ::: "memory");                         \
    __builtin_amdgcn_sched_barrier(0);                                         \
    __builtin_amdgcn_s_barrier();                        /* B1 */              \
    STAGE(BUF, OFFU);                                                          \
    __builtin_amdgcn_sched_barrier(0);                                         \
    VMC_N();                                                                   \
    __builtin_amdgcn_sched_barrier(0);                                         \
    __builtin_amdgcn_s_barrier();                        /* B2 */              \
    LDA(a0, pAk0[NBUF]); LDB(b0, pBk0[NBUF]);            /* R3 */              \
    __builtin_amdgcn_sched_barrier(0);                                         \
    __builtin_amdgcn_s_setprio(1);                                             \
    MFMA_KS(a1, b1);                                     /* ks1 */             \
    __builtin_amdgcn_s_setprio(0);                                             \
  } while (0)

#define TILE_P(BUF, NBUF) do {                           /* t = NT-2 */        \
    LDA(a1, pAk1[BUF]); LDB(b1, pBk1[BUF]);                                    \
    __builtin_amdgcn_sched_barrier(0);                                         \
    __builtin_amdgcn_s_setprio(1);                                             \
    MFMA_KS(a0, b0);                                                           \
    __builtin_amdgcn_s_setprio(0);                                             \
    asm volatile("s_waitcnt lgkmcnt(0)" ::: "memory");                         \
    __builtin_amdgcn_sched_barrier(0);                                         \
    asm volatile("s_waitcnt vmcnt(0)" ::: "memory");                           \
    __builtin_amdgcn_sched_barrier(0);                                         \
    __builtin_amdgcn_s_barrier();                                              \
    LDA(a0, pAk0[NBUF]); LDB(b0, pBk0[NBUF]);                                  \
    __builtin_amdgcn_sched_barrier(0);                                         \
    __builtin_amdgcn_s_setprio(1);                                             \
    MFMA_KS(a1, b1);                                                           \
    __builtin_amdgcn_s_setprio(0);                                             \
  } while (0)

#define TILE_L(BUF) do {                                 /* t = NT-1 */        \
    LDA(a1, pAk1[BUF]); LDB(b1, pBk1[BUF]);                                    \
    __builtin_amdgcn_sched_barrier(0);                                         \
    MFMA_KS(a0, b0);                                                           \
    MFMA_KS(a1, b1);                                                           \
  } while (0)

#define GEMM_V2_BODY(BN_)                                                      \
  constexpr int NF_ = (BN_) / 64;                                              \
  constexpr int ASW_ = 4;                                                      \
  constexpr int BSW_ = (BN_) / 64;                                             \
  constexpr int BUFSZ_ = 16384 + (BN_) * 64;                                   \
  const int tid = threadIdx.x;                                                 \
  const int lane = tid & 63;                                                   \
  const int w = tid >> 6;                                                      \
  const int wm = w >> 2, wn = w & 3;                                           \
  const int l15 = lane & 15, lg = lane >> 4;                                   \
  const int goff = (w * 8 + (lane >> 3)) * DIM_ + ((lane & 7) ^ (lane >> 3)) * 8; \
  const int x7 = l15 & 7;                                                      \
  const int lr0 = l15 * 64 + ((lg ^ x7) * 8);                                  \
  const int lr1 = l15 * 64 + (((4 | lg) ^ x7) * 8);                            \
  const u16* pAk0[2] = {lds + wm * 8192 + lr0, lds + BUFSZ_ + wm * 8192 + lr0};\
  const u16* pAk1[2] = {lds + wm * 8192 + lr1, lds + BUFSZ_ + wm * 8192 + lr1};\
  const u16* pBk0[2] = {lds + 16384 + wn * ((BN_)*16) + lr0,                   \
                        lds + BUFSZ_ + 16384 + wn * ((BN_)*16) + lr0};         \
  const u16* pBk1[2] = {lds + 16384 + wn * ((BN_)*16) + lr1,                   \
                        lds + BUFSZ_ + 16384 + wn * ((BN_)*16) + lr1};         \
  f32x4 acc[8][NF_];                                                           \
  _Pragma("unroll") for (int i = 0; i < 8; ++i)                                \
    _Pragma("unroll") for (int j = 0; j < NF_; ++j)                            \
        acc[i][j] = (f32x4){0.f, 0.f, 0.f, 0.f};                               \
  bf16x8 a0[8], a1[8], b0[NF_], b1[NF_];                                       \
  STAGE(0, 0);                                                                 \
  STAGE(1, 64);                                                                \
  __builtin_amdgcn_sched_barrier(0);                                           \
  VMC_N();                                                                     \
  __builtin_amdgcn_sched_barrier(0);                                           \
  __builtin_amdgcn_s_barrier();                                                \
  LDA(a0, pAk0[0]); LDB(b0, pBk0[0]);                                          \
  for (int t = 0; t < NT_ - 2; t += 2) {                                       \
    TILE_N(0, 1, 128);                                                         \
    TILE_N(1, 0, 192);                                                         \
    sA += 128; sB += 128;                                                      \
  }                                                                            \
  TILE_P(0, 1);                                                                \
  TILE_L(1);

// ---------------- QKV: BN=256, 384 blocks, bf16 out ----------------
__global__ __launch_bounds__(512, 2) void gemm256_qkv_kernel(
    const u16* __restrict__ xb, const u16* __restrict__ wqb, const u16* __restrict__ wkb,
    const u16* __restrict__ wvb, u16* __restrict__ qb, u16* __restrict__ kb,
    u16* __restrict__ vb) {
  __shared__ __align__(16) u16 lds[65536];  // 128 KB

  const int bid = blockIdx.x;
  const int logical = (bid & 7) * 48 + (bid >> 3);
  const int mt = logical / 24;
  const int rem = logical % 24;
  const int z = rem >> 3;
  const int nt = rem & 7;
  const u16* Wm = (z == 0) ? wqb : (z == 1) ? wkb : wvb;
  u16* out = (z == 0) ? qb : (z == 1) ? kb : vb;

  const u16* sA = xb + (size_t)(mt * 256) * DIM_;
  const u16* sB = Wm + (size_t)(nt * 256) * DIM_;

  GEMM_V2_BODY(256)

#pragma unroll
  for (int mi = 0; mi < 8; ++mi)
#pragma unroll
    for (int ni = 0; ni < 4; ++ni) {
      const int row = mt * 256 + wm * 128 + mi * 16 + lg * 4;
      const int col = nt * 256 + wn * 64 + ni * 16 + l15;
#pragma unroll
      for (int r = 0; r < 4; ++r)
        out[(size_t)(row + r) * DIM_ + col] = f2b(acc[mi][ni][r]);
    }
}

// ---------------- O-projection: BN=128, 256 blocks = 1 exact round, f32 out ----------------
__global__ __launch_bounds__(512, 2) void gemm_out_v2_kernel(const u16* __restrict__ A,
                                                             const u16* __restrict__ W,
                                                             float* __restrict__ Cf) {
  __shared__ __align__(16) u16 lds[49152];  // 96 KB
  const int bid = blockIdx.x;
  const int logical = (bid & 7) * 32 + (bid >> 3);
  const int mt = logical >> 4;
  const int nt = logical & 15;

  const u16* sA = A + (size_t)(mt * 256) * DIM_;
  const u16* sB = W + (size_t)(nt * 128) * DIM_;

  GEMM_V2_BODY(128)

#pragma unroll
  for (int mi = 0; mi < 8; ++mi)
#pragma unroll
    for (int ni = 0; ni < 2; ++ni) {
      const int row = mt * 256 + wm * 128 + mi * 16 + lg * 4;
      const int col = nt * 128 + wn * 32 + ni * 16 + l15;
#pragma unroll
      for (int r = 0; r < 4; ++r)
        Cf[(size_t)(row + r) * DIM_ + col] = acc[mi][ni][r];
    }
}

// ==================================================================================
// Causal flash attention, swapped-QK^T 32x32 structure + T14 async-STAGE dbuf:
// K and V tiles double-buffered (64 KB LDS). Per tile: issue gloadK(t+1->alt) +
// V global reg-loads EARLY (before compute t); V LDS-transpose writes AFTER compute;
// one __syncthreads() per tile (its vmcnt(0)+lgkmcnt(0)+barrier = the dbuf protocol).
// HBM latency + transpose VALU hide under QK^T/softmax/PV.
// ==================================================================================
#define CEXP 0.12751744f  /* (1/sqrt(128)) * log2(e) */

__global__ __launch_bounds__(256, 2) void attn_kernel(const u16* __restrict__ q,
                                                      const u16* __restrict__ k,
                                                      const u16* __restrict__ v,
                                                      u16* __restrict__ ao) {
  // kTl: 2 x [64][128] u16 @ 0, 8192 ; vTl: 2 x [128][64] u16 @ 16384, 24576
  __shared__ __align__(16) u16 smem[32768];  // 64 KB
  u16* kTl = smem;
  u16* vTl = smem + 16384;

  const int qt   = blockIdx.z ? (int)blockIdx.x : (int)(gridDim.x - 1 - blockIdx.x);
  const int head = blockIdx.y;
  const int b    = blockIdx.z;
  const int t = threadIdx.x;
  const int lane = t & 63;
  const int w = t >> 6;
  const int l31 = lane & 31;
  const int hi = lane >> 5;
  const int kxor = (lane & 7) << 3;
  const int qrow0 = qt * 128 + w * 32;
  const size_t bS = (size_t)b * S_;

  bf16x8 qf[8];
  {
    const u16* qrow = q + (bS + qrow0 + l31) * DIM_ + head * HD_;
#pragma unroll
    for (int st = 0; st < 8; ++st)
      qf[st] = *(const bf16x8*)(qrow + st * 16 + hi * 8);
  }

  f32x16 accO[4];
#pragma unroll
  for (int db = 0; db < 4; ++db)
#pragma unroll
    for (int r = 0; r < 16; ++r) accO[db][r] = 0.f;
  float m = -1e30f, l = 0.f;

  const int tmax_w = 2 * qt + (w >> 1);
  const int ttend = 2 * qt + 1;

  bf16x8 vv[4];

  // ---- staging helpers (buf in {0,1}) ----
  auto stageK = [&](int buf, int tt) {
#pragma unroll
    for (int p = 0; p < 4; ++p) {
      const int cid = p * 256 + w * 64 + lane;
      const int kr = cid >> 4;
      const int cg = (cid & 15) ^ (kr & 7);
      gload16(k + (bS + tt * 64 + kr) * DIM_ + head * HD_ + cg * 8,
              kTl + buf * 8192 + (p * 256 + w * 64) * 8);
    }
  };
  auto loadV = [&](int tt) {
#pragma unroll
    for (int p = 0; p < 4; ++p) {
      const int dchunk = p * 4 + w;
      vv[p] = *(const bf16x8*)(v + (bS + tt * 64 + lane) * DIM_ + head * HD_ + dchunk * 8);
    }
  };
  auto writeV = [&](int buf) {
#pragma unroll
    for (int p = 0; p < 4; ++p) {
      const int dchunk = p * 4 + w;
#pragma unroll
      for (int j = 0; j < 8; ++j) {
        const int d = dchunk * 8 + j;
        vTl[buf * 8192 + d * 64 + (lane ^ ((d & 7) << 3))] = (u16)vv[p][j];
      }
    }
  };

  // ---- prologue: stage tile 0 -> buf 0 ----
  stageK(0, 0);
  loadV(0);
  writeV(0);
  __syncthreads();

  for (int tt = 0; tt <= ttend; ++tt) {
    const int cur = tt & 1;
    const int alt = cur ^ 1;

    // T14: issue next tile's K-DMA + V reg-loads before compute
    if (tt + 1 <= ttend) {
      stageK(alt, tt + 1);
      loadV(tt + 1);
    }

    if (tt <= tmax_w) {
      const u16* kB = kTl + cur * 8192;
      const u16* vB = vTl + cur * 8192;
      f32x16 sA, sB;
#pragma unroll
      for (int r = 0; r < 16; ++r) { sA[r] = 0.f; sB[r] = 0.f; }
      __builtin_amdgcn_s_setprio(1);
#pragma unroll
      for (int st = 0; st < 8; ++st) {
        const int dc = st * 16 + hi * 8;
        bf16x8 k0 = *(const bf16x8*)(kB + l31 * 128 + (dc ^ kxor));
        bf16x8 k1 = *(const bf16x8*)(kB + (32 + l31) * 128 + (dc ^ kxor));
        sA = __builtin_amdgcn_mfma_f32_32x32x16_bf16(k0, qf[st], sA, 0, 0, 0);
        sB = __builtin_amdgcn_mfma_f32_32x32x16_bf16(k1, qf[st], sB, 0, 0, 0);
      }
      __builtin_amdgcn_s_setprio(0);

      const int qg = qrow0 + l31;
      if (tt * 64 + 63 > qrow0) {
        const int kb = tt * 64 + 4 * hi;
#pragma unroll
        for (int r = 0; r < 16; ++r) {
          const int kg = kb + (r & 3) + 8 * (r >> 2);
          sA[r] = (kg <= qg) ? sA[r] : -1e30f;
          sB[r] = (kg + 32 <= qg) ? sB[r] : -1e30f;
        }
      }

      float mx[8];
#pragma unroll
      for (int i = 0; i < 8; ++i)
        mx[i] = fmaxf(fmaxf(sA[i], sA[i + 8]), fmaxf(sB[i], sB[i + 8]));
#pragma unroll
      for (int i = 0; i < 4; ++i) mx[i] = fmaxf(mx[i], mx[i + 4]);
      float pm = fmaxf(fmaxf(mx[0], mx[1]), fmaxf(mx[2], mx[3]));
      pm = fmaxf(pm, __shfl_xor(pm, 32));
      const float mN = fmaxf(m, pm);
      if (!__all(pm - m <= 90.5f)) {  // T13 defer-max
        const float osc = exp2f((m - mN) * CEXP);
        l *= osc;
#pragma unroll
        for (int db = 0; db < 4; ++db)
#pragma unroll
          for (int r = 0; r < 16; ++r) accO[db][r] *= osc;
        m = mN;
      }
      const float mc = m * CEXP;
      float lsv[4] = {0.f, 0.f, 0.f, 0.f};
#pragma unroll
      for (int r = 0; r < 16; ++r) {
        const float pa = exp2f(__builtin_fmaf(sA[r], CEXP, -mc));
        const float pb = exp2f(__builtin_fmaf(sB[r], CEXP, -mc));
        sA[r] = pa; sB[r] = pb;
        lsv[r & 3] += pa + pb;
      }
      float ls = (lsv[0] + lsv[1]) + (lsv[2] + lsv[3]);
      ls += __shfl_xor(ls, 32);
      l += ls;

#define PV_STEP(ARR, R0, ST2)                                                      \
      {                                                                            \
        u32 a0 = cvtpk(ARR[(R0) + 0], ARR[(R0) + 1]);                              \
        u32 a1 = cvtpk(ARR[(R0) + 2], ARR[(R0) + 3]);                              \
        u32 b0 = cvtpk(ARR[(R0) + 4], ARR[(R0) + 5]);                              \
        u32 b1 = cvtpk(ARR[(R0) + 6], ARR[(R0) + 7]);                              \
        asm("v_permlane32_swap_b32 %0, %1" : "+v"(a0), "+v"(b0));                  \
        asm("v_permlane32_swap_b32 %0, %1" : "+v"(a1), "+v"(b1));                  \
        union { u32 uu[4]; bf16x8 v8; } pf;                                        \
        pf.uu[0] = a0; pf.uu[1] = a1; pf.uu[2] = b0; pf.uu[3] = b1;                \
        const int ko = (ST2) * 16 + hi * 8;                                        \
        __builtin_amdgcn_s_setprio(1);                                             \
        _Pragma("unroll")                                                          \
        for (int db = 0; db < 4; ++db) {                                           \
          const int dr = db * 32 + l31;                                            \
          bf16x8 vf = *(const bf16x8*)(vB + dr * 64 + (ko ^ kxor));                \
          accO[db] =                                                               \
              __builtin_amdgcn_mfma_f32_32x32x16_bf16(vf, pf.v8, accO[db], 0, 0, 0); \
        }                                                                          \
        __builtin_amdgcn_s_setprio(0);                                             \
      }
      PV_STEP(sA, 0, 0)
      PV_STEP(sA, 8, 1)
      PV_STEP(sB, 0, 2)
      PV_STEP(sB, 8, 3)
#undef PV_STEP
    }

    // commit next tile's V transpose after compute (overlaps with other waves' PV)
    if (tt + 1 <= ttend) writeV(alt);
    __syncthreads();  // vmcnt(0)+lgkmcnt(0)+barrier: K-DMA landed, V writes visible
  }

  // ---- epilogue: normalize, transpose O^T->O through LDS, coalesced store ----
  const float linv = 1.0f / l;
  u16* oT = smem + w * 4352;
#pragma unroll
  for (int db = 0; db < 4; ++db)
#pragma unroll
    for (int q4 = 0; q4 < 4; ++q4) {
      const int dbase = db * 32 + q4 * 8 + hi * 4;
      const u32 lo = cvtpk(accO[db][q4 * 4 + 0] * linv, accO[db][q4 * 4 + 1] * linv);
      const u32 hiw = cvtpk(accO[db][q4 * 4 + 2] * linv, accO[db][q4 * 4 + 3] * linv);
      *(u32*)(oT + l31 * 136 + dbase) = lo;
      *(u32*)(oT + l31 * 136 + dbase + 2) = hiw;
    }
  __syncthreads();
#pragma unroll
  for (int i = 0; i < 8; ++i) {
    const int cid = i * 64 + lane;
    const int qloc = cid >> 4;
    const int c = cid & 15;
    const bf16x8 val = *(const bf16x8*)(oT + qloc * 136 + c * 8);
    *(bf16x8*)(ao + (bS + qrow0 + qloc) * DIM_ + head * HD_ + c * 8) = val;
  }
}

// ---------- launch ----------
extern "C" void kernel_launch(void* const* d_in, const int* in_sizes, int n_in,
                              void* d_out, int out_size, void* d_ws, size_t ws_size,
                              hipStream_t stream) {
  const float* x  = (const float*)d_in[0];
  const float* wq = (const float*)d_in[2];
  const float* wk = (const float*)d_in[3];
  const float* wv = (const float*)d_in[4];
  const float* wo = (const float*)d_in[5];

  char* ws = (char*)d_ws;
  size_t off = 0;
  auto carve = [&](size_t bytes) { char* p = ws + off; off += bytes; return p; };
  u16* xb   = (u16*)carve((size_t)M_ * DIM_ * 2);
  u16* wqb  = (u16*)carve((size_t)DIM_ * DIM_ * 2);
  u16* wkb  = (u16*)carve((size_t)DIM_ * DIM_ * 2);
  u16* wvb  = (u16*)carve((size_t)DIM_ * DIM_ * 2);
  u16* wob  = (u16*)carve((size_t)DIM_ * DIM_ * 2);
  u16* qb   = (u16*)carve((size_t)M_ * DIM_ * 2);
  u16* kb   = (u16*)carve((size_t)M_ * DIM_ * 2);
  u16* vb   = (u16*)carve((size_t)M_ * DIM_ * 2);
  u16* aob  = (u16*)carve((size_t)M_ * DIM_ * 2);
  float* cosT = (float*)carve((size_t)S_ * 64 * 4);
  float* sinT = (float*)carve((size_t)S_ * 64 * 4);
  if (off > ws_size) return;

  dim3 gc(1024, 5);
  convert5_kernel<<<gc, 256, 0, stream>>>(x, wq, wk, wv, wo, xb, wqb, wkb, wvb, wob);
  rope_table_kernel<<<512, 256, 0, stream>>>(cosT, sinT);

  gemm256_qkv_kernel<<<384, 512, 0, stream>>>(xb, wqb, wkb, wvb, qb, kb, vb);

  dim3 gr((B_ * S_ * H_ * 8) / 256, 2);
  rope_apply_kernel<<<gr, 256, 0, stream>>>(qb, kb, cosT, sinT);

  dim3 ga(S_ / 128, H_, B_);
  attn_kernel<<<ga, 256, 0, stream>>>(qb, kb, vb, aob);

  gemm_out_v2_kernel<<<256, 512, 0, stream>>>(aob, wob, (float*)d_out);
}